// Round 1
// baseline (2503.856 us; speedup 1.0000x reference)
//
#include <hip/hip_runtime.h>

#define ANG 9
#define OH 48
#define OW 48
#define IHH 432
#define IWW 432
#define CIN 64
#define COUT 64
#define ND 9
#define NB 4

// One thread computes 8 consecutive-tile cout outputs for one (b, d, oh, ow).
// W accesses are wave-uniform (co0 from blockIdx) -> scalar loads (SMEM pipe).
// x bounds handled via clamp+select (no divergent branches in hot loop).
__global__ __launch_bounds__(192)
void cost_volume_direct(const float* __restrict__ x,
                        const float* __restrict__ w,
                        float* __restrict__ out) {
    const int ow      = threadIdx.x;                   // 0..47
    const int oh      = blockIdx.y * 4 + threadIdx.y;  // 0..47
    const int co_tile = blockIdx.x & 7;                // 0..7  (fastest: L2 reuse of x rows)
    const int dd      = blockIdx.x >> 3;               // 0..8
    const int b       = blockIdx.z;                    // 0..3
    const int d       = dd - 4;
    const int co0     = co_tile * 8;

    int dilat, pad;
    if (d < 0)       { dilat = (-d) * ANG + 1; pad = 36 * (-d); }
    else if (d == 0) { dilat = 1;              pad = 0; }
    else             { dilat = d * ANG - 1;    pad = 36 * d - (ANG - 1); }

    const int ih0 = oh * ANG - pad;
    const int iw0 = ow * ANG - pad;

    float acc[8];
#pragma unroll
    for (int i = 0; i < 8; ++i) acc[i] = 0.f;

    const float* xb = x + (size_t)b * CIN * IHH * IWW;

    for (int kh = 0; kh < ANG; ++kh) {
        const int ih = ih0 + kh * dilat;
        if ((unsigned)ih >= (unsigned)IHH) continue;   // whole row OOB -> contributes 0
        const float* xrow_base = xb + (size_t)ih * IWW;
        const float* wrow      = w + kh * ANG;         // + ci*81 + co*5184 later

        for (int ci = 0; ci < CIN; ++ci) {
            const float* xrow = xrow_base + (size_t)ci * (IHH * IWW);

            // Gather the 9 taps for this row (masked, branch-free).
            float xv[ANG];
#pragma unroll
            for (int kw = 0; kw < ANG; ++kw) {
                const int iw  = iw0 + kw * dilat;
                const bool ok = ((unsigned)iw < (unsigned)IWW);
                const float v = xrow[ok ? iw : 0];     // clamped -> always safe
                xv[kw] = ok ? v : 0.f;
            }

            const float* wc = wrow + ci * (ANG * ANG);
#pragma unroll
            for (int i = 0; i < 8; ++i) {
                const float* wi = wc + (size_t)(co0 + i) * (CIN * ANG * ANG);
#pragma unroll
                for (int kw = 0; kw < ANG; ++kw) {
                    acc[i] = fmaf(xv[kw], wi[kw], acc[i]);
                }
            }
        }
    }

    // out layout: [B][COUT][ND][OH][OW]
#pragma unroll
    for (int i = 0; i < 8; ++i) {
        const size_t o = ((((size_t)b * COUT + (co0 + i)) * ND + dd) * OH + oh) * OW + ow;
        out[o] = acc[i];
    }
}

extern "C" void kernel_launch(void* const* d_in, const int* in_sizes, int n_in,
                              void* d_out, int out_size, void* d_ws, size_t ws_size,
                              hipStream_t stream) {
    const float* x   = (const float*)d_in[0];
    const float* w   = (const float*)d_in[1];
    float*       out = (float*)d_out;

    dim3 grid(8 * ND, OH / 4, NB);   // (co_tile,d) fastest, oh_tile, b
    dim3 block(OW, 4, 1);            // 192 threads = 3 waves
    cost_volume_direct<<<grid, block, 0, stream>>>(x, w, out);
}

// Round 2
// 319.354 us; speedup vs baseline: 7.8404x; 7.8404x over previous
//
#include <hip/hip_runtime.h>

#define ANG 9
#define OHW 48
#define IMG 432
#define CIN 64
#define COUT 64
#define ND 9
#define NB 4
#define NVIEW 81
#define NSPAT 2304   // 48*48
#define NTOT 9216    // NB*NSPAT

using f32x4 = __attribute__((ext_vector_type(4))) float;
using s16x8 = __attribute__((ext_vector_type(8))) short;

__device__ __forceinline__ unsigned short f2bf(float f) {
    unsigned u = __float_as_uint(f);
    unsigned r = (u + 0x7FFFu + ((u >> 16) & 1u)) >> 16;   // RNE
    return (unsigned short)r;
}

// ---------------- kernel 1: pack W -> Aw[81][128][64] bf16 -------------------
// Aw[uv][co][ci]      = W[co][ci][u][v]          (var0, for d<=0)
// Aw[uv][64+co][ci]   = W[co][ci][8-u][8-v]      (var1, for d>0)
__global__ void k_wpack(const float* __restrict__ w, unsigned short* __restrict__ aw) {
    int idx = blockIdx.x * 256 + threadIdx.x;
    if (idx >= NVIEW * 128 * 64) return;
    int ci = idx & 63;
    int m  = (idx >> 6) & 127;
    int uv = idx >> 13;
    int u = uv / 9, v = uv % 9;
    int co = m & 63, var = m >> 6;
    int uu = var ? 8 - u : u;
    int vv = var ? 8 - v : v;
    aw[idx] = f2bf(w[((size_t)(co * 64 + ci) * 9 + uu) * 9 + vv]);
}

// ---------------- kernel 2: pack x -> xbT[81][9216][64] bf16 -----------------
// xbT[u*9+v][b*2304 + h*48 + w][ci] = x[b][ci][9h+u][9w+v]
__global__ __launch_bounds__(432)
void k_packx(const float* __restrict__ x, unsigned short* __restrict__ xbt) {
    __shared__ float lds[8][432];
    const int h = blockIdx.x, u = blockIdx.y, b = blockIdx.z;
    const int t = threadIdx.x;
    const int ih = 9 * h + u;
    const int v = t / 48, wq = t % 48;
    const int n = b * NSPAT + h * 48 + wq;
    const size_t obase = ((size_t)(u * 9 + v) * NTOT + n) * 64;

    for (int ci0 = 0; ci0 < 64; ci0 += 8) {
#pragma unroll
        for (int c = 0; c < 8; ++c) {
            lds[c][t] = x[(((size_t)b * 64 + ci0 + c) * IMG + ih) * IMG + t];
        }
        __syncthreads();
        union { unsigned short us[8]; uint4 u4; } pk;
#pragma unroll
        for (int c = 0; c < 8; ++c) pk.us[c] = f2bf(lds[c][9 * wq + v]);
        *reinterpret_cast<uint4*>(&xbt[obase + ci0]) = pk.u4;
        __syncthreads();
    }
}

// ---------------- kernel 3: per-view GEMM, Y = Aw * xview --------------------
// Y[uv][co128][n] (bf16), M=128, N=9216, K=64.  16x16x32 bf16 MFMA.
// Block: one view, N-tile of 64 (wave-per-16-cols). 4 waves.
__global__ __launch_bounds__(256)
void k_gemm(const unsigned short* __restrict__ aw,
            const unsigned short* __restrict__ xbt,
            unsigned short* __restrict__ y) {
    const int uv   = blockIdx.y;
    const int lane = threadIdx.x & 63;
    const int wave = threadIdx.x >> 6;
    const int n0   = blockIdx.x * 64 + wave * 16;
    const int lr   = lane & 15;   // output col (n) / A row (m) selector
    const int lh   = lane >> 4;   // k-group selector

    const unsigned short* bp = xbt + ((size_t)uv * NTOT + n0 + lr) * 64 + lh * 8;
    const s16x8 b0 = *reinterpret_cast<const s16x8*>(bp);
    const s16x8 b1 = *reinterpret_cast<const s16x8*>(bp + 32);

    f32x4 acc[8];
#pragma unroll
    for (int mf = 0; mf < 8; ++mf) acc[mf] = (f32x4){0.f, 0.f, 0.f, 0.f};

    const unsigned short* ab = aw + ((size_t)uv * 128 + lr) * 64 + lh * 8;
#pragma unroll
    for (int mf = 0; mf < 8; ++mf) {
        const s16x8 a0 = *reinterpret_cast<const s16x8*>(ab + (size_t)mf * 16 * 64);
        const s16x8 a1 = *reinterpret_cast<const s16x8*>(ab + (size_t)mf * 16 * 64 + 32);
        acc[mf] = __builtin_amdgcn_mfma_f32_16x16x32_bf16(a0, b0, acc[mf], 0, 0, 0);
        acc[mf] = __builtin_amdgcn_mfma_f32_16x16x32_bf16(a1, b1, acc[mf], 0, 0, 0);
    }

    // D layout: col = lane&15, row = (lane>>4)*4 + reg   [m89-verified]
#pragma unroll
    for (int mf = 0; mf < 8; ++mf) {
#pragma unroll
        for (int r = 0; r < 4; ++r) {
            const int co = mf * 16 + lh * 4 + r;
            y[((size_t)uv * 128 + co) * NTOT + n0 + lr] = f2bf(acc[mf][r]);
        }
    }
}

// ---------------- kernel 4: shift-gather-sum over 81 views -------------------
// out[b][co][dd][h][w] = sum_uv Y[uv][var(dd)*64+co][b][h-d'(u-4)][w-d'(v-4)]
// LDS: zero-padded 80x80 per var -> no bounds masks.
__global__ __launch_bounds__(576)
void k_gather(const unsigned short* __restrict__ y, float* __restrict__ out) {
    __shared__ unsigned short lds[2 * 80 * 80];
    const int co = blockIdx.x, b = blockIdx.y;
    const int tid = threadIdx.x;

    for (int i = tid; i < 2 * 80 * 80; i += 576) lds[i] = 0;

    const int var = tid / 288;            // which co-variant slab this thread stages
    const int e0  = (tid % 288) * 8;      // element offset within 48x48 slab
    const int srow = e0 / 48, scol = e0 % 48;
    const int ldst = var * 6400 + (16 + srow) * 80 + 16 + scol;
    const unsigned short* ybase =
        y + ((size_t)(var * 64 + co)) * NTOT + (size_t)b * NSPAT + e0;

    int center[4];
    int pos[4];
#pragma unroll
    for (int k = 0; k < 4; ++k) {
        pos[k] = tid + 576 * k;
        const int h = pos[k] / 48, w = pos[k] % 48;
        center[k] = (16 + h) * 80 + (16 + w);
    }
    float acc[4][9];
#pragma unroll
    for (int k = 0; k < 4; ++k)
#pragma unroll
        for (int dd = 0; dd < 9; ++dd) acc[k][dd] = 0.f;

    uint4 pre = *reinterpret_cast<const uint4*>(ybase);   // view 0
    __syncthreads();                                       // zero-fill done

    for (int uv = 0; uv < NVIEW; ++uv) {
        *reinterpret_cast<uint4*>(&lds[ldst]) = pre;
        __syncthreads();
        if (uv < NVIEW - 1)
            pre = *reinterpret_cast<const uint4*>(ybase + (size_t)(uv + 1) * 128 * NTOT);

        const int u = uv / 9, v = uv % 9;
        const int step = (u - 4) * 80 + (v - 4);
#pragma unroll
        for (int k = 0; k < 4; ++k) {
            int addr = center[k] + 4 * step;               // dd=0 -> +4*step
#pragma unroll
            for (int dd = 0; dd < 9; ++dd) {
                const int a2 = addr + (dd > 4 ? 6400 : 0); // var1 slab for d'>0
                const unsigned short t = lds[a2];
                acc[k][dd] += __uint_as_float(((unsigned)t) << 16);
                addr -= step;
            }
        }
        __syncthreads();
    }

#pragma unroll
    for (int k = 0; k < 4; ++k)
#pragma unroll
        for (int dd = 0; dd < 9; ++dd)
            out[((size_t)(b * 64 + co) * 9 + dd) * NSPAT + pos[k]] = acc[k][dd];
}

// ---------------- fallback: round-1 direct conv (used if ws too small) -------
__global__ __launch_bounds__(192)
void cost_volume_direct(const float* __restrict__ x,
                        const float* __restrict__ w,
                        float* __restrict__ out) {
    const int ow      = threadIdx.x;
    const int oh      = blockIdx.y * 4 + threadIdx.y;
    const int co_tile = blockIdx.x & 7;
    const int dd      = blockIdx.x >> 3;
    const int b       = blockIdx.z;
    const int d       = dd - 4;
    const int co0     = co_tile * 8;

    int dilat, pad;
    if (d < 0)       { dilat = (-d) * ANG + 1; pad = 36 * (-d); }
    else if (d == 0) { dilat = 1;              pad = 0; }
    else             { dilat = d * ANG - 1;    pad = 36 * d - (ANG - 1); }

    const int ih0 = oh * ANG - pad;
    const int iw0 = ow * ANG - pad;

    float acc[8];
#pragma unroll
    for (int i = 0; i < 8; ++i) acc[i] = 0.f;

    const float* xb = x + (size_t)b * CIN * IMG * IMG;
    for (int kh = 0; kh < ANG; ++kh) {
        const int ih = ih0 + kh * dilat;
        if ((unsigned)ih >= (unsigned)IMG) continue;
        const float* xrow_base = xb + (size_t)ih * IMG;
        const float* wrow      = w + kh * ANG;
        for (int ci = 0; ci < CIN; ++ci) {
            const float* xrow = xrow_base + (size_t)ci * (IMG * IMG);
            float xv[ANG];
#pragma unroll
            for (int kw = 0; kw < ANG; ++kw) {
                const int iw  = iw0 + kw * dilat;
                const bool ok = ((unsigned)iw < (unsigned)IMG);
                const float vv = xrow[ok ? iw : 0];
                xv[kw] = ok ? vv : 0.f;
            }
            const float* wc = wrow + ci * (ANG * ANG);
#pragma unroll
            for (int i = 0; i < 8; ++i) {
                const float* wi = wc + (size_t)(co0 + i) * (CIN * ANG * ANG);
#pragma unroll
                for (int kw = 0; kw < ANG; ++kw)
                    acc[i] = fmaf(xv[kw], wi[kw], acc[i]);
            }
        }
    }
#pragma unroll
    for (int i = 0; i < 8; ++i) {
        const size_t o = ((((size_t)b * COUT + (co0 + i)) * ND + dd) * OHW + oh) * OHW + ow;
        out[o] = acc[i];
    }
}

extern "C" void kernel_launch(void* const* d_in, const int* in_sizes, int n_in,
                              void* d_out, int out_size, void* d_ws, size_t ws_size,
                              hipStream_t stream) {
    const float* x   = (const float*)d_in[0];
    const float* w   = (const float*)d_in[1];
    float*       out = (float*)d_out;

    const size_t AW_BYTES  = (size_t)NVIEW * 128 * 64 * 2;        //   1,327,104
    const size_t XBT_BYTES = (size_t)NVIEW * NTOT * 64 * 2;       //  95,551,488
    const size_t Y_BYTES   = (size_t)NVIEW * 128 * NTOT * 2;      // 191,102,976
    const size_t NEED      = AW_BYTES + XBT_BYTES + Y_BYTES;      // 287,981,568

    if (ws_size >= NEED) {
        unsigned short* aw  = (unsigned short*)d_ws;
        unsigned short* xbt = (unsigned short*)((char*)d_ws + AW_BYTES);
        unsigned short* yb  = (unsigned short*)((char*)d_ws + AW_BYTES + XBT_BYTES);

        k_wpack<<<dim3((NVIEW * 128 * 64 + 255) / 256), dim3(256), 0, stream>>>(w, aw);
        k_packx<<<dim3(OHW, ANG, NB), dim3(432), 0, stream>>>(x, xbt);
        k_gemm <<<dim3(NTOT / 64, NVIEW), dim3(256), 0, stream>>>(aw, xbt, yb);
        k_gather<<<dim3(COUT, NB), dim3(576), 0, stream>>>(yb, out);
    } else {
        dim3 grid(8 * ND, OHW / 4, NB);
        dim3 block(OHW, 4, 1);
        cost_volume_direct<<<grid, block, 0, stream>>>(x, w, out);
    }
}